// Round 5
// baseline (326.781 us; speedup 1.0000x reference)
//
#include <hip/hip_runtime.h>

// ResFCEventuallyLayer — (1) fused fp32->bf16 pre-convert into d_ws,
// (2) 256x256 modulo-software-pipelined bf16 MFMA GEMM + fused epilogue.
//   rs   = x @ W^T            (einsum "bj,ij->bi": both operands K-major)
//   out1 = relu(1 - beta + rs)
//   res  = relu(1 - (beta_res - (x + out1)));  LeakyReLU(res>=0) == identity
//
// R11: rotate the quadrant order per tile so EVERY fragment is ds_read one
// full phase before its consuming MFMA (true modulo schedule, zero extra
// VGPRs). Phase = {read next frag (4-8 b128) || 16 MFMA on prev frags}.
// Tile orders: even(buf0): Q10,Q00,Q01,Q11; odd(buf1): Q00,Q10,Q11,Q01.
// Array refill slots (verified free-one-phase-before-use):
//   E1 rd af0<-b0 | E2 rd bf1<-b0, vmcnt(0),BAR | E3 rd bf0<-b1, BAR
//   E4 rd af0<-b1, STAGE8->b0 | O1 rd af1<-b1 | O2 rd bf1<-b1, vmcnt(0),BAR
//   O3 rd bf0<-b0', BAR | O4 rd af1<-b0', STAGE8->b1
// Fences (minimal, each justified):
//   WAR: stages->buf0 at E4 fenced by E3-end BAR (buf0's last read, E2's
//        bf1, is consumed by E3's MFMA -> done before each wave's arrival).
//        Mirror: stages->buf1 at O4 fenced by O3-end BAR.
//   RAW: per-wave vmcnt(0) at E2/O2 then BAR -> all waves' stages (issued
//        2 phases = ~1000cy earlier) visible before E3/O3 reads.
//   Post-loop VMCNT(0): no LDS-DMA outlives the workgroup.

#define NDIM 4096

typedef __bf16 bf16x8 __attribute__((ext_vector_type(8)));
typedef float f32x4 __attribute__((ext_vector_type(4)));

__device__ unsigned short f2bf(float f) {
    unsigned int x;
    __builtin_memcpy(&x, &f, 4);
    unsigned int r = x + 0x7FFFu + ((x >> 16) & 1u);   // round-to-nearest-even
    return (unsigned short)(r >> 16);
}

__device__ unsigned int pack_bf2(float lo, float hi) {
    return (unsigned int)f2bf(lo) | ((unsigned int)f2bf(hi) << 16);
}

// Direct global->LDS DMA, 16 B per lane: wave-uniform LDS base + lane*16.
__device__ inline void gload16(const uint4* g, unsigned int* l) {
    __builtin_amdgcn_global_load_lds(
        (const __attribute__((address_space(1))) unsigned int*)g,
        (__attribute__((address_space(3))) unsigned int*)l,
        16, 0, 0);
}

// Phase 1 (fused): fp32 -> packed bf16 for BOTH X and W in one launch.
// 8 elements per thread; 8192 blocks per matrix.
__global__ void convert_f32_bf16_kernel(const float* X, unsigned int* Xbf,
                                        const float* W, unsigned int* Wbf) {
    unsigned int bid = blockIdx.x;
    const float* src;
    unsigned int* dst;
    if (bid < 8192) { src = X; dst = Xbf; }
    else            { src = W; dst = Wbf; bid -= 8192; }
    const size_t i = ((size_t)bid * blockDim.x + threadIdx.x) * 8;
    float4 v0 = *(const float4*)(src + i);
    float4 v1 = *(const float4*)(src + i + 4);
    uint4 u;
    u.x = pack_bf2(v0.x, v0.y);
    u.y = pack_bf2(v0.z, v0.w);
    u.z = pack_bf2(v1.x, v1.y);
    u.w = pack_bf2(v1.z, v1.w);
    *(uint4*)(dst + i / 2) = u;
}

#define BAR()   __builtin_amdgcn_s_barrier()
#define VMCNT(n) asm volatile("s_waitcnt vmcnt(" #n ")" ::: "memory")
#define PRIO(x) __builtin_amdgcn_s_setprio(x)

// Stage one half-tile (2 rounds x 8KB). buf/h are literals.
#define STAGE_A(buf, h, S) do { \
    gload16(Ab4 + (offA[2*(h)]   + (S)*8), &sAU[buf][(2*(h))*2048   + wq]); \
    gload16(Ab4 + (offA[2*(h)+1] + (S)*8), &sAU[buf][(2*(h)+1)*2048 + wq]); \
} while (0)
#define STAGE_B(buf, h, S) do { \
    gload16(Bb4 + (offB[2*(h)]   + (S)*8), &sBU[buf][(2*(h))*2048   + wq]); \
    gload16(Bb4 + (offB[2*(h)+1] + (S)*8), &sBU[buf][(2*(h)+1)*2048 + wq]); \
} while (0)
// All 4 halves of one K-tile (8 loads).
#define STAGE_ALL(buf, S) do { \
    STAGE_A(buf, 0, S); STAGE_A(buf, 1, S); \
    STAGE_B(buf, 0, S); STAGE_B(buf, 1, S); \
} while (0)

// ds-read a 4-mt A group (8 x ds_read_b128) / 2-nt B group (4 x b128).
#define READ_A4(dst, pbuf, mt0) do { \
    _Pragma("unroll") for (int _m = 0; _m < 4; _m++) { \
        dst[_m][0] = (pbuf)[afB + ((mt0) + _m) * 128]; \
        dst[_m][1] = (pbuf)[afB + ((mt0) + _m) * 128 + 64]; } \
} while (0)
#define READ_B2(dst, pbuf, nt0) do { \
    _Pragma("unroll") for (int _n = 0; _n < 2; _n++) { \
        dst[_n][0] = (pbuf)[bfB + ((nt0) + _n) * 128]; \
        dst[_n][1] = (pbuf)[bfB + ((nt0) + _n) * 128 + 64]; } \
} while (0)

// One C-quadrant x K=64: ksub outer -> 8 independent MFMAs per pass.
#define MM16(afr, bfr, mt0, nt0) do { \
    _Pragma("unroll") for (int _k = 0; _k < 2; _k++) \
    _Pragma("unroll") for (int _m = 0; _m < 4; _m++) \
    _Pragma("unroll") for (int _n = 0; _n < 2; _n++) \
        acc[(mt0)+_m][(nt0)+_n] = __builtin_amdgcn_mfma_f32_16x16x32_bf16( \
            afr[_m][_k], bfr[_n][_k], acc[(mt0)+_m][(nt0)+_n], 0, 0, 0); \
} while (0)

// Phase 2: 256x256 tile, BK=64, 8 waves (2Mx4N), modulo-scheduled loop.
__global__ void __launch_bounds__(512, 2)
ResFCEventuallyLayer_82205674045459_kernel(
    const unsigned int* Xbf, const unsigned int* Wbf,
    const float* X, const float* Bp, const float* Br,
    float* out)
{
    // Per buffer: 256 rows x 64 k x bf16 = 32KB = 32 subtiles x 1KB.
    // Subtile (sr = row>>4, sc = kcol>>5) at byte (sr*2+sc)*1024; within:
    // r = row&15, phys chunk-in-row = logical chunk ^ ((r>>3)<<1).
    __shared__ __align__(16) unsigned int sAU[2][8192];
    __shared__ __align__(16) unsigned int sBU[2][8192];

    const int t    = threadIdx.x;      // 0..511
    const int lane = t & 63;
    const int wave = t >> 6;           // 0..7
    const int quad = lane >> 4;        // 0..3
    const int l16  = lane & 15;
    const int wm   = wave >> 2;        // 0..1: 128-row half
    const int wn   = wave & 3;         // 0..3: 64-col quarter
    const int wq   = wave * 256;       // LDS uint offset of wave's 1KB DMA slice

    // 256 blocks total (= 1/CU); bijective XCD swizzle (256 % 8 == 0).
    const int bid = blockIdx.x;
    const int swz = ((bid & 7) << 5) | (bid >> 3);
    const int bm0 = (swz >> 4) * 256;
    const int bn0 = (swz & 15) * 256;

    const uint4* Ab4 = (const uint4*)Xbf;   // 512 uint4 per global row
    const uint4* Bb4 = (const uint4*)Wbf;

    // Staging inverse-swizzle: DMA round rr writes phys chunks p = rr*512 + t
    // (lane*16B within wave slice). Invert phys->logical for the global src.
    int offA[4], offB[4];
#pragma unroll
    for (int rr = 0; rr < 4; rr++) {
        const int p   = rr * 512 + t;
        const int r   = (p >> 2) & 15;
        const int sub = p >> 6;               // 0..31
        const int sr  = sub >> 1, sc = sub & 1;
        const int c8  = (p & 3) ^ (((r >> 3) & 1) << 1);
        const int row = sr * 16 + r;
        const int gc  = sc * 4 + c8;          // logical 8-col chunk in K-tile
        offA[rr] = (bm0 + row) * 512 + gc;
        offB[rr] = (bn0 + row) * 512 + gc;
    }

    // Fragment ds_read addressing (matches the staged swizzle):
    // byte = subtile*1024 + l16*64 + (quad*16 ^ ((l16>>3)<<5)); conflict-free.
    const int laneByte = l16 * 64 + ((quad * 16) ^ (((l16 >> 3) & 1) << 5));
    const int afB = (wm * 16384 + laneByte) >> 4;   // bf16x8 units
    const int bfB = (wn * 8192  + laneByte) >> 4;

    const bf16x8* pA0 = (const bf16x8*)sAU[0];
    const bf16x8* pA1 = (const bf16x8*)sAU[1];
    const bf16x8* pB0 = (const bf16x8*)sBU[0];
    const bf16x8* pB1 = (const bf16x8*)sBU[1];

    f32x4 acc[8][4];
#pragma unroll
    for (int i = 0; i < 8; i++)
#pragma unroll
        for (int j = 0; j < 4; j++)
#pragma unroll
            for (int r = 0; r < 4; r++)
                acc[i][j][r] = 0.0f;

    bf16x8 af0[4][2], af1[4][2], bf0[2][2], bf1[2][2];

    // Prologue: stage tile0->buf0 and tile1->buf1; drain tile0; pre-read
    // tile0's first-quadrant operands (af1, bf0).
    STAGE_ALL(0, 0);
    STAGE_ALL(1, 1);
    VMCNT(8);          // own tile0 loads landed (tile1's 8 still in flight)
    BAR();             // all waves' tile0 stages visible
    READ_B2(bf0, pB0, 0);
    READ_A4(af1, pA0, 4);

    // 64 K-tiles, 2 per iteration: even tile in buf0, odd in buf1.
    for (int j = 0; j < 32; j++) {
        const int S2 = (2 * j + 2) & 63;      // wrap: harmless refetch at end
        const int S3 = (2 * j + 3) & 63;

        // ---- even tile 2j (buf0): Q10,Q00,Q01,Q11 ----
        // E1: read af0<-buf0 (for E2/E3); MFMA Q10 on af1,bf0 (pre-read)
        READ_A4(af0, pA0, 0);
        PRIO(1); MM16(af1, bf0, 4, 0); PRIO(0);
        // E2: read bf1<-buf0 (for E3/E4); MFMA Q00; drain stages -> buf1 ready
        READ_B2(bf1, pB0, 2);
        PRIO(1); MM16(af0, bf0, 0, 0); PRIO(0);
        VMCNT(0); BAR();
        // E3: read bf0<-buf1 (for O1/O2); MFMA Q01
        READ_B2(bf0, pB1, 0);
        PRIO(1); MM16(af0, bf1, 0, 2); PRIO(0);
        BAR();            // fences E4's stages (buf0 last read E2, used E3)
        // E4: read af0<-buf1 (for O1/O4); stage tile 2j+2 -> buf0; MFMA Q11
        READ_A4(af0, pA1, 0);
        STAGE_ALL(0, S2);
        PRIO(1); MM16(af1, bf1, 4, 2); PRIO(0);

        // ---- odd tile 2j+1 (buf1): Q00,Q10,Q11,Q01 ----
        // O1: read af1<-buf1 (for O2/O3); MFMA Q00 on af0,bf0
        READ_A4(af1, pA1, 4);
        PRIO(1); MM16(af0, bf0, 0, 0); PRIO(0);
        // O2: read bf1<-buf1 (for O3/O4); MFMA Q10; drain stages -> buf0 ready
        READ_B2(bf1, pB1, 2);
        PRIO(1); MM16(af1, bf0, 4, 0); PRIO(0);
        VMCNT(0); BAR();
        // O3: read bf0<-buf0 (next even tile); MFMA Q11
        READ_B2(bf0, pB0, 0);
        PRIO(1); MM16(af1, bf1, 4, 2); PRIO(0);
        BAR();            // fences O4's stages (buf1 last read O2, used O3)
        // O4: read af1<-buf0 (next even); stage tile 2j+3 -> buf1; MFMA Q01
        READ_A4(af1, pA0, 4);
        STAGE_ALL(1, S3);
        PRIO(1); MM16(af0, bf1, 0, 2); PRIO(0);
    }
    VMCNT(0);             // no LDS-DMA outlives the workgroup

    // Fused epilogue. C/D layout: n(col) = lane&15, m(row) = quad*4 + reg.
    const float one_m_beta = 1.0f - Bp[0];
#pragma unroll
    for (int nt = 0; nt < 4; nt++) {
        const int n = bn0 + wn * 64 + nt * 16 + l16;
        const float br = Br[n];
#pragma unroll
        for (int mt = 0; mt < 8; mt++) {
            const int mbase = bm0 + wm * 128 + mt * 16 + quad * 4;
#pragma unroll
            for (int r = 0; r < 4; r++) {
                const size_t idx = (size_t)(mbase + r) * NDIM + n;
                float v = acc[mt][nt][r] + one_m_beta;
                if (v < 0.0f) v = 0.0f;                 // relu(1 - beta + rowsum)
                float res = 1.0f - br + X[idx] + v;
                if (res < 0.0f) res = 0.0f;             // relu; leaky on relu == id
                out[idx] = res;
            }
        }
    }
}

// Fallback (R6 kernel, proven): in-loop conversion, no workspace needed.
__global__ void resfc_fallback_kernel(
    const float* X, const float* W,
    const float* Bp, const float* Br,
    float* out)
{
    __shared__ __align__(16) unsigned int sA[128 * 16];
    __shared__ __align__(16) unsigned int sB[128 * 16];

    const int t    = threadIdx.x;
    const int lane = t & 63;
    const int wave = t >> 6;
    const int quad = lane >> 4;
    const int l16  = lane & 15;
    const int wm   = wave >> 1;
    const int wn   = wave & 1;

    const int bm0 = blockIdx.y * 128;
    const int bn0 = blockIdx.x * 128;

    const float* gA[4];
    const float* gB[4];
    int ldsIdx[4];
    for (int c = 0; c < 4; c++) {
        const int ch   = t + c * 256;
        const int row  = ch >> 3;
        const int col4 = ch & 7;
        gA[c] = X + (size_t)(bm0 + row) * NDIM + col4 * 4;
        gB[c] = W + (size_t)(bn0 + row) * NDIM + col4 * 4;
        ldsIdx[c] = row * 16 + col4 * 2;
    }

    const bf16x8* pa = (const bf16x8*)sA + (wm * 64 + l16) * 4 + quad;
    const bf16x8* pb = (const bf16x8*)sB + (wn * 64 + l16) * 4 + quad;

    f32x4 acc[4][4];
    for (int i = 0; i < 4; i++)
        for (int j = 0; j < 4; j++)
            for (int r = 0; r < 4; r++)
                acc[i][j][r] = 0.0f;

    for (int k0 = 0; k0 < NDIM; k0 += 32) {
        float4 va[4], vb[4];
        for (int c = 0; c < 4; c++) {
            va[c] = *(const float4*)(gA[c] + k0);
            vb[c] = *(const float4*)(gB[c] + k0);
        }
        __syncthreads();
        for (int c = 0; c < 4; c++) {
            uint2 ua, ub;
            ua.x = pack_bf2(va[c].x, va[c].y);
            ua.y = pack_bf2(va[c].z, va[c].w);
            ub.x = pack_bf2(vb[c].x, vb[c].y);
            ub.y = pack_bf2(vb[c].z, vb[c].w);
            *(uint2*)(sA + ldsIdx[c]) = ua;
            *(uint2*)(sB + ldsIdx[c]) = ub;
        }
        __syncthreads();

        bf16x8 af[4], bfr[4];
        for (int mt = 0; mt < 4; mt++) af[mt]  = pa[mt * 64];
        for (int nt = 0; nt < 4; nt++) bfr[nt] = pb[nt * 64];

        for (int mt = 0; mt < 4; mt++)
            for (int nt = 0; nt < 4; nt++)
                acc[mt][nt] = __builtin_amdgcn_mfma_f32_16x16x32_bf16(
                    af[mt], bfr[nt], acc[mt][nt], 0, 0, 0);
    }

    const float one_m_beta = 1.0f - Bp[0];
    for (int nt = 0; nt < 4; nt++) {
        const int n = bn0 + wn * 64 + nt * 16 + l16;
        const float br = Br[n];
        for (int mt = 0; mt < 4; mt++) {
            const int mbase = bm0 + wm * 64 + mt * 16 + quad * 4;
            for (int r = 0; r < 4; r++) {
                const size_t idx = (size_t)(mbase + r) * NDIM + n;
                float v = acc[mt][nt][r] + one_m_beta;
                if (v < 0.0f) v = 0.0f;
                float res = 1.0f - br + X[idx] + v;
                if (res < 0.0f) res = 0.0f;
                out[idx] = res;
            }
        }
    }
}

extern "C" void kernel_launch(void* const* d_in, const int* in_sizes, int n_in,
                              void* d_out, int out_size, void* d_ws, size_t ws_size,
                              hipStream_t stream) {
    (void)in_sizes; (void)n_in; (void)out_size;

    const float* X  = (const float*)d_in[0];
    const float* W  = (const float*)d_in[1];
    const float* Bp = (const float*)d_in[2];
    const float* Br = (const float*)d_in[3];
    float* out      = (float*)d_out;

    const size_t elems   = (size_t)NDIM * NDIM;          // 16.7M per matrix
    const size_t bf_need = elems * 2 * 2;                // Xbf + Wbf, 2 B each

    if (ws_size >= bf_need) {
        unsigned int* Xbf = (unsigned int*)d_ws;
        unsigned int* Wbf = (unsigned int*)d_ws + elems / 2;   // uint = 2 bf16

        hipLaunchKernelGGL(convert_f32_bf16_kernel, dim3(16384), dim3(256),
                           0, stream, X, Xbf, W, Wbf);
        hipLaunchKernelGGL(ResFCEventuallyLayer_82205674045459_kernel,
                           dim3(256), dim3(512), 0, stream, Xbf, Wbf, X, Bp, Br, out);
    } else {
        hipLaunchKernelGGL(resfc_fallback_kernel,
                           dim3(NDIM / 128, NDIM / 128), dim3(256), 0, stream,
                           X, W, Bp, Br, out);
    }
}